// Round 2
// baseline (3080.381 us; speedup 1.0000x reference)
//
#include <hip/hip_runtime.h>
#include <math.h>

// Problem constants
#define B 16
#define H 1024
#define W 1024
#define TOPK 5000
#define SCORES_TH 0.2f

// workspace layout
#define CAP 65536          // max candidates per batch (expected ~42k)
#define SELCAP 8192        // max selected (threshold-passing) per batch
#define NB 4928            // histogram buckets over value bits[31:12]
#define OFFB 0x3E4CC       // (bits(0.2f) >> 12)

#define BX 32
#define BY 8

// ---------------------------------------------------------------------------
// K1: fused double 5x5 NMS + compaction of candidates (> 0.2) into per-batch
// lists with 64-bit keys (value_bits << 32) | ~idx  (desc value, asc index).
// ---------------------------------------------------------------------------
__global__ __launch_bounds__(256) void nms_compact(
    const float* __restrict__ s,
    unsigned* __restrict__ counts,
    unsigned long long* __restrict__ cand)
{
    const int b  = blockIdx.z;
    const int x0 = blockIdx.x * BX;
    const int y0 = blockIdx.y * BY;
    const float* sb = s + (size_t)b * (H * W);

    __shared__ float sT[BY + 8][BX + 8 + 1];   // 16 x 41  (raw scores, halo 4)
    __shared__ float n1[BY + 4][BX + 4 + 1];   // 12 x 37  (nms pass 1, halo 2)

    const int tid = threadIdx.y * BX + threadIdx.x;

    // load raw scores with halo 4; OOB = -inf (reduce_window identity)
    for (int k = tid; k < (BX + 8) * (BY + 8); k += 256) {
        int lx = k % (BX + 8), ly = k / (BX + 8);
        int gx = x0 - 4 + lx, gy = y0 - 4 + ly;
        float v = -INFINITY;
        if (gx >= 0 && gx < W && gy >= 0 && gy < H) v = sb[gy * W + gx];
        sT[ly][lx] = v;
    }
    __syncthreads();

    // NMS pass 1 on the (BX+4)x(BY+4) halo-2 region
    for (int k = tid; k < (BX + 4) * (BY + 4); k += 256) {
        int lx = k % (BX + 4), ly = k / (BX + 4);
        int gx = x0 - 2 + lx, gy = y0 - 2 + ly;
        float r = -INFINITY;                   // marker for OOB (excluded from max)
        if (gx >= 0 && gx < W && gy >= 0 && gy < H) {
            float v = sT[ly + 2][lx + 2];
            float m = -INFINITY;
            #pragma unroll
            for (int dy = 0; dy < 5; ++dy)
                #pragma unroll
                for (int dx = 0; dx < 5; ++dx)
                    m = fmaxf(m, sT[ly + dy][lx + dx]);
            r = (v == m) ? v : 0.0f;
        }
        n1[ly][lx] = r;
    }
    __syncthreads();

    // NMS pass 2 on the BX x BY output region + compaction
    {
        const int tx = threadIdx.x, ty = threadIdx.y;
        float v = n1[ty + 2][tx + 2];
        float m = -INFINITY;
        #pragma unroll
        for (int dy = 0; dy < 5; ++dy)
            #pragma unroll
            for (int dx = 0; dx < 5; ++dx)
                m = fmaxf(m, n1[ty + dy][tx + dx]);
        float r = (v == m) ? v : 0.0f;
        if (r > SCORES_TH) {
            unsigned idx = (unsigned)((y0 + ty) * W + (x0 + tx));
            unsigned long long key =
                ((unsigned long long)__float_as_uint(r) << 32) | (unsigned)(~idx);
            unsigned p = atomicAdd(&counts[b], 1u);   // compiler wave-aggregates
            if (p < CAP) cand[(size_t)b * CAP + p] = key;
        }
    }
}

// ---------------------------------------------------------------------------
// K2: per-batch histogram radix-select: find bucket threshold T so that
// #(bucket >= T) >= 5000 (or select all if fewer), gather selected into sel[].
// ---------------------------------------------------------------------------
__global__ __launch_bounds__(256) void select_thresh(
    const unsigned* __restrict__ counts,
    const unsigned long long* __restrict__ cand,
    unsigned long long* __restrict__ sel,
    unsigned* __restrict__ selC)
{
    const int b = blockIdx.x;
    __shared__ unsigned hist[NB];
    __shared__ int Tsh;
    __shared__ unsigned cnt;
    const int tid = threadIdx.x;

    for (int i = tid; i < NB; i += 256) hist[i] = 0;
    if (tid == 0) cnt = 0;
    __syncthreads();

    unsigned M = counts[b]; if (M > CAP) M = CAP;
    const unsigned long long* cb = cand + (size_t)b * CAP;

    for (unsigned i = tid; i < M; i += 256) {
        unsigned bits = (unsigned)(cb[i] >> 32);
        int bk = (int)(bits >> 12) - OFFB;
        bk = bk < 0 ? 0 : (bk >= NB ? NB - 1 : bk);
        atomicAdd(&hist[bk], 1u);
    }
    __syncthreads();

    if (tid == 0) {
        unsigned acc = 0; int T = 0;
        for (int bk = NB - 1; bk >= 0; --bk) {
            acc += hist[bk];
            if (acc >= TOPK) { T = bk; break; }
        }
        Tsh = T;                                  // M < TOPK -> T=0 (select all)
    }
    __syncthreads();
    const int T = Tsh;

    for (unsigned i = tid; i < M; i += 256) {
        unsigned long long key = cb[i];
        unsigned bits = (unsigned)(key >> 32);
        int bk = (int)(bits >> 12) - OFFB;
        bk = bk < 0 ? 0 : (bk >= NB ? NB - 1 : bk);
        if (bk >= T) {
            unsigned p = atomicAdd(&cnt, 1u);
            if (p < SELCAP) sel[(size_t)b * SELCAP + p] = key;
        }
    }
    __syncthreads();
    if (tid == 0) selC[b] = cnt > SELCAP ? SELCAP : cnt;
}

// ---------------------------------------------------------------------------
// K3: exact rank by counting (keys unique -> ranks are a permutation),
// then 5x5 softmax sub-pixel refinement, scatter to out[rank].
// grid (8, B), block 1024: 8*1024 covers SELCAP candidates per batch.
// ---------------------------------------------------------------------------
__global__ __launch_bounds__(1024) void rank_refine(
    const float* __restrict__ s,
    const unsigned long long* __restrict__ sel,
    const unsigned* __restrict__ selC,
    float* __restrict__ out)
{
    const int b = blockIdx.y;
    const unsigned C = selC[b];
    __shared__ unsigned long long keys[SELCAP];   // 64 KB
    const int tid = threadIdx.x;
    const unsigned long long* sb = sel + (size_t)b * SELCAP;

    for (int i = tid; i < SELCAP; i += 1024)
        keys[i] = (i < (int)C) ? sb[i] : 0ull;
    __syncthreads();

    const unsigned i = blockIdx.x * 1024u + (unsigned)tid;
    if (i >= C) return;

    const unsigned long long my = keys[i];
    unsigned rank = 0;
    for (unsigned j = 0; j < C; ++j)              // LDS broadcast reads
        rank += (keys[j] > my) ? 1u : 0u;
    if (rank >= TOPK) return;

    float v = __uint_as_float((unsigned)(my >> 32));
    unsigned idx = ~((unsigned)my);
    int y = (int)(idx >> 10), x = (int)(idx & 1023);

    const float* smb = s + (size_t)b * (H * W);
    float wsum = 0.f, ox = 0.f, oy = 0.f;
    #pragma unroll
    for (int dy = -2; dy <= 2; ++dy) {
        #pragma unroll
        for (int dx = -2; dx <= 2; ++dx) {
            int yy = y + dy, xx = x + dx;
            bool inb = (yy >= 0 && yy < H && xx >= 0 && xx < W);
            int yc = min(max(yy, 0), H - 1), xc = min(max(xx, 0), W - 1);
            float p = smb[yc * W + xc];
            float lg = inb ? p * 10.0f : -1e9f;   // 1/TEMPERATURE = 10
            float e = expf(lg);                   // exp(-1e9) underflows to 0
            wsum += e; ox += e * (float)dx; oy += e * (float)dy;
        }
    }
    float offx = ox / wsum, offy = oy / wsum;
    out[((size_t)b * TOPK + rank) * 2 + 0] = (float)x + offx;
    out[((size_t)b * TOPK + rank) * 2 + 1] = (float)y + offy;
    out[(size_t)B * TOPK * 2 + (size_t)b * TOPK + rank] = v;
}

// ---------------------------------------------------------------------------
extern "C" void kernel_launch(void* const* d_in, const int* in_sizes, int n_in,
                              void* d_out, int out_size, void* d_ws, size_t ws_size,
                              hipStream_t stream)
{
    const float* s = (const float*)d_in[0];
    float* out = (float*)d_out;
    char* ws = (char*)d_ws;

    unsigned* counts            = (unsigned*)ws;                              // 64 B
    unsigned* selC              = (unsigned*)(ws + 64);                       // 64 B
    unsigned long long* sel     = (unsigned long long*)(ws + 128);            // 1 MB
    unsigned long long* cand    = (unsigned long long*)(ws + 128 + (size_t)B * SELCAP * 8); // 8 MB

    hipMemsetAsync(counts, 0, 64, stream);
    hipMemsetAsync(d_out, 0, (size_t)out_size * sizeof(float), stream);

    nms_compact<<<dim3(W / BX, H / BY, B), dim3(BX, BY), 0, stream>>>(s, counts, cand);
    select_thresh<<<dim3(B), dim3(256), 0, stream>>>(counts, cand, sel, selC);
    rank_refine<<<dim3(SELCAP / 1024, B), dim3(1024), 0, stream>>>(s, sel, selC, out);
}

// Round 6
// 358.988 us; speedup vs baseline: 8.5807x; 8.5807x over previous
//
#include <hip/hip_runtime.h>
#include <math.h>

// Problem constants
#define B 16
#define H 1024
#define W 1024
#define TOPK 5000
#define SCORES_TH 0.2f

// workspace layout
#define CAP 65536          // max candidates per batch (expected ~42k)
#define SELCAP 8192        // max selected (threshold-passing) per batch
#define NB 4928            // histogram buckets over value bits[31:12]
#define OFFB 0x3E4CC       // (bits(0.2f) >> 12)
#define CSTRIDE 32         // counts padded 32 uints = 128 B apart (cacheline)

#define TILE 64            // 64x64 output tile per block, 256 threads
#define CBUF 1024          // per-block candidate cap (strict peaks <= ~484)

// ---------------------------------------------------------------------------
// K1: fused double 5x5 NMS (separable max) + block-aggregated compaction.
// Keys: (value_bits << 32) | ~idx  (desc value, asc index) — unique per pixel.
// ---------------------------------------------------------------------------
__global__ __launch_bounds__(256) void nms_compact(
    const float* __restrict__ s,
    unsigned* __restrict__ counts,
    unsigned long long* __restrict__ cand)
{
    const int b  = blockIdx.z;
    const int x0 = blockIdx.x * TILE;
    const int y0 = blockIdx.y * TILE;
    const float* sb = s + (size_t)b * (H * W);

    // raw tile + halo 4:   72 x 72   (stride 76 -> 16B-aligned rows)
    __shared__ float sT[72][76];                 // 21,888 B
    // horizontal 5-max of sT (cols 0..67):
    __shared__ float hm1[72][68];                // 19,584 B
    // NMS pass 1 (halo 2): 68 x 68
    __shared__ float n1[68][69];                 // 18,768 B
    __shared__ unsigned lcnt, lbase;

    // cbuf aliases sT (dead after n1 is built); hm2 aliases hm1
    unsigned long long* cbuf = (unsigned long long*)&sT[0][0];   // 8 KB < 21 KB
    float (*hm2)[64] = (float(*)[64])&hm1[0][0];                 // 17.4 KB < 19.5 KB

    const int tid = threadIdx.y * 16 + threadIdx.x;   // block is 256 = 16x16
    if (tid == 0) lcnt = 0;

    // ---- phase 1: load 72x72 raw scores (halo 4), OOB = -inf --------------
    const bool xedge = (x0 == 0) | (x0 + TILE == W);
    if (!xedge) {
        // rows of 18 aligned float4s starting at gx = x0-4
        for (int k = tid; k < 72 * 18; k += 256) {
            int row = k / 18, q = k - row * 18;
            int gy = y0 - 4 + row;
            float4 v;
            if (gy >= 0 && gy < H)
                v = *(const float4*)(sb + (size_t)gy * W + (x0 - 4) + 4 * q);
            else
                v = make_float4(-INFINITY, -INFINITY, -INFINITY, -INFINITY);
            *(float4*)&sT[row][4 * q] = v;
        }
    } else {
        for (int k = tid; k < 72 * 72; k += 256) {
            int row = k / 72, col = k - row * 72;
            int gy = y0 - 4 + row, gx = x0 - 4 + col;
            float v = -INFINITY;
            if (gx >= 0 && gx < W && gy >= 0 && gy < H) v = sb[(size_t)gy * W + gx];
            sT[row][col] = v;
        }
    }
    __syncthreads();

    // ---- phase 2: horizontal 5-max, rows 0..71, cols 0..67 ----------------
    for (int k = tid; k < 72 * 68; k += 256) {
        int r = k / 68, c = k - r * 68;
        float m = sT[r][c];
        m = fmaxf(m, sT[r][c + 1]); m = fmaxf(m, sT[r][c + 2]);
        m = fmaxf(m, sT[r][c + 3]); m = fmaxf(m, sT[r][c + 4]);
        hm1[r][c] = m;
    }
    __syncthreads();

    // ---- phase 3: vertical 5-max + compare  -> NMS pass 1 (68x68, halo 2) -
    for (int k = tid; k < 68 * 68; k += 256) {
        int ly = k / 68, lx = k - ly * 68;
        int gy = y0 - 2 + ly, gx = x0 - 2 + lx;
        float r = -INFINITY;                      // OOB marker = -inf padding
        if (gx >= 0 && gx < W && gy >= 0 && gy < H) {
            float v = sT[ly + 2][lx + 2];
            float m = hm1[ly][lx];
            m = fmaxf(m, hm1[ly + 1][lx]); m = fmaxf(m, hm1[ly + 2][lx]);
            m = fmaxf(m, hm1[ly + 3][lx]); m = fmaxf(m, hm1[ly + 4][lx]);
            r = (v == m) ? v : 0.0f;
        }
        n1[ly][lx] = r;
    }
    __syncthreads();   // sT, hm1 now dead -> cbuf/hm2 aliases valid

    // ---- phase 4: horizontal 5-max of n1, rows 0..67, cols 0..63 ----------
    for (int k = tid; k < 68 * 64; k += 256) {
        int r = k >> 6, c = k & 63;
        float m = n1[r][c];
        m = fmaxf(m, n1[r][c + 1]); m = fmaxf(m, n1[r][c + 2]);
        m = fmaxf(m, n1[r][c + 3]); m = fmaxf(m, n1[r][c + 4]);
        hm2[r][c] = m;
    }
    __syncthreads();

    // ---- phase 5: vertical 5-max + compare -> NMS pass 2, compact to LDS --
    for (int k = tid; k < 64 * 64; k += 256) {
        int ty = k >> 6, tx = k & 63;
        float v = n1[ty + 2][tx + 2];
        float m = hm2[ty][tx];
        m = fmaxf(m, hm2[ty + 1][tx]); m = fmaxf(m, hm2[ty + 2][tx]);
        m = fmaxf(m, hm2[ty + 3][tx]); m = fmaxf(m, hm2[ty + 4][tx]);
        float r = (v == m) ? v : 0.0f;
        if (r > SCORES_TH) {
            unsigned idx = (unsigned)((y0 + ty) * W + (x0 + tx));
            unsigned long long key =
                ((unsigned long long)__float_as_uint(r) << 32) | (unsigned)(~idx);
            unsigned p = atomicAdd(&lcnt, 1u);    // LDS atomic
            if (p < CBUF) cbuf[p] = key;
        }
    }
    __syncthreads();

    // ---- phase 6: one global atomic per block, then coalesced flush -------
    unsigned n = lcnt; if (n > CBUF) n = CBUF;
    if (tid == 0) lbase = atomicAdd(&counts[b * CSTRIDE], n);
    __syncthreads();
    unsigned base = lbase;
    for (unsigned k = tid; k < n; k += 256)
        if (base + k < CAP) cand[(size_t)b * CAP + base + k] = cbuf[k];
}

// ---------------------------------------------------------------------------
// K2: per-batch histogram radix-select: find bucket threshold T so that
// #(bucket >= T) >= 5000 (or select all if fewer), gather selected into sel[].
// ---------------------------------------------------------------------------
__global__ __launch_bounds__(256) void select_thresh(
    const unsigned* __restrict__ counts,
    const unsigned long long* __restrict__ cand,
    unsigned long long* __restrict__ sel,
    unsigned* __restrict__ selC)
{
    const int b = blockIdx.x;
    __shared__ unsigned hist[NB];
    __shared__ int Tsh;
    __shared__ unsigned cnt;
    const int tid = threadIdx.x;

    for (int i = tid; i < NB; i += 256) hist[i] = 0;
    if (tid == 0) cnt = 0;
    __syncthreads();

    unsigned M = counts[b * CSTRIDE]; if (M > CAP) M = CAP;
    const unsigned long long* cb = cand + (size_t)b * CAP;

    for (unsigned i = tid; i < M; i += 256) {
        unsigned bits = (unsigned)(cb[i] >> 32);
        int bk = (int)(bits >> 12) - OFFB;
        bk = bk < 0 ? 0 : (bk >= NB ? NB - 1 : bk);
        atomicAdd(&hist[bk], 1u);
    }
    __syncthreads();

    if (tid == 0) {
        unsigned acc = 0; int T = 0;
        for (int bk = NB - 1; bk >= 0; --bk) {
            acc += hist[bk];
            if (acc >= TOPK) { T = bk; break; }
        }
        Tsh = T;                                  // M < TOPK -> T=0 (select all)
    }
    __syncthreads();
    const int T = Tsh;

    for (unsigned i = tid; i < M; i += 256) {
        unsigned long long key = cb[i];
        unsigned bits = (unsigned)(key >> 32);
        int bk = (int)(bits >> 12) - OFFB;
        bk = bk < 0 ? 0 : (bk >= NB ? NB - 1 : bk);
        if (bk >= T) {
            unsigned p = atomicAdd(&cnt, 1u);
            if (p < SELCAP) sel[(size_t)b * SELCAP + p] = key;
        }
    }
    __syncthreads();
    if (tid == 0) selC[b] = cnt > SELCAP ? SELCAP : cnt;
}

// ---------------------------------------------------------------------------
// K3: exact rank by counting (keys unique -> ranks are a permutation),
// then 5x5 softmax sub-pixel refinement, scatter to out[rank].
// grid (8, B), block 1024.
// ---------------------------------------------------------------------------
__global__ __launch_bounds__(1024) void rank_refine(
    const float* __restrict__ s,
    const unsigned long long* __restrict__ sel,
    const unsigned* __restrict__ selC,
    float* __restrict__ out)
{
    const int b = blockIdx.y;
    const unsigned C = selC[b];
    __shared__ unsigned long long keys[SELCAP];   // 64 KB
    const int tid = threadIdx.x;
    const unsigned long long* sb = sel + (size_t)b * SELCAP;

    for (int i = tid; i < SELCAP; i += 1024)
        keys[i] = (i < (int)C) ? sb[i] : 0ull;
    __syncthreads();

    const unsigned i = blockIdx.x * 1024u + (unsigned)tid;
    if (i >= C) return;

    const unsigned long long my = keys[i];
    unsigned rank = 0;
    for (unsigned j = 0; j < C; ++j)              // LDS broadcast reads
        rank += (keys[j] > my) ? 1u : 0u;
    if (rank >= TOPK) return;

    float v = __uint_as_float((unsigned)(my >> 32));
    unsigned idx = ~((unsigned)my);
    int y = (int)(idx >> 10), x = (int)(idx & 1023);

    const float* smb = s + (size_t)b * (H * W);
    float wsum = 0.f, ox = 0.f, oy = 0.f;
    #pragma unroll
    for (int dy = -2; dy <= 2; ++dy) {
        #pragma unroll
        for (int dx = -2; dx <= 2; ++dx) {
            int yy = y + dy, xx = x + dx;
            bool inb = (yy >= 0 && yy < H && xx >= 0 && xx < W);
            int yc = min(max(yy, 0), H - 1), xc = min(max(xx, 0), W - 1);
            float p = smb[yc * W + xc];
            float lg = inb ? p * 10.0f : -1e9f;   // 1/TEMPERATURE = 10
            float e = expf(lg);                   // exp(-1e9) underflows to 0
            wsum += e; ox += e * (float)dx; oy += e * (float)dy;
        }
    }
    float offx = ox / wsum, offy = oy / wsum;
    out[((size_t)b * TOPK + rank) * 2 + 0] = (float)x + offx;
    out[((size_t)b * TOPK + rank) * 2 + 1] = (float)y + offy;
    out[(size_t)B * TOPK * 2 + (size_t)b * TOPK + rank] = v;
}

// ---------------------------------------------------------------------------
extern "C" void kernel_launch(void* const* d_in, const int* in_sizes, int n_in,
                              void* d_out, int out_size, void* d_ws, size_t ws_size,
                              hipStream_t stream)
{
    const float* s = (const float*)d_in[0];
    float* out = (float*)d_out;
    char* ws = (char*)d_ws;

    unsigned* counts            = (unsigned*)ws;                              // 16*32*4 = 2 KB
    unsigned* selC              = (unsigned*)(ws + 2048);                     // 64 B
    unsigned long long* sel     = (unsigned long long*)(ws + 2048 + 64);      // 1 MB
    unsigned long long* cand    = (unsigned long long*)(ws + 2048 + 64 + (size_t)B * SELCAP * 8); // 8 MB

    hipMemsetAsync(counts, 0, B * CSTRIDE * sizeof(unsigned), stream);
    hipMemsetAsync(d_out, 0, (size_t)out_size * sizeof(float), stream);

    nms_compact<<<dim3(W / TILE, H / TILE, B), dim3(16, 16), 0, stream>>>(s, counts, cand);
    select_thresh<<<dim3(B), dim3(256), 0, stream>>>(counts, cand, sel, selC);
    rank_refine<<<dim3(SELCAP / 1024, B), dim3(1024), 0, stream>>>(s, sel, selC, out);
}

// Round 7
// 321.647 us; speedup vs baseline: 9.5769x; 1.1161x over previous
//
#include <hip/hip_runtime.h>
#include <math.h>

// Problem constants
#define B 16
#define H 1024
#define W 1024
#define TOPK 5000
#define SCORES_TH 0.2f

// workspace layout
#define CAP 65536          // max candidates per batch (expected ~42k)
#define SELCAP 8192        // max selected (threshold-passing) per batch
#define NB 4928            // histogram buckets over value bits[31:12]
#define OFFB 0x3E4CC       // (bits(0.2f) >> 12)
#define CSTRIDE 32         // counts padded 32 uints = 128 B apart (cacheline)

#define TX 32              // 32x32 output tile per block, 256 threads
#define TY 32
#define CBUF 256           // per-block candidate cap (expected ~41, strict max ~144)

// ---------------------------------------------------------------------------
// K1: fused double 5x5 NMS (separable max) + block-aggregated compaction.
// 32x32 tile -> ~18.3 KB LDS -> 8 blocks/CU (was 60 KB -> 2 blocks/CU).
// Keys: (value_bits << 32) | ~idx  (desc value, asc index) — unique per pixel.
// ---------------------------------------------------------------------------
__global__ __launch_bounds__(256) void nms_compact(
    const float* __restrict__ s,
    unsigned* __restrict__ counts,
    unsigned long long* __restrict__ cand)
{
    const int b  = blockIdx.z;
    const int x0 = blockIdx.x * TX;
    const int y0 = blockIdx.y * TY;
    const float* sb = s + (size_t)b * (H * W);

    __shared__ float sT[40][44];     // raw tile + halo 4 (40x40 used), 7040 B
    __shared__ float hm1[40][37];    // horizontal 5-max (40x36 used), 5920 B
    __shared__ float n1[36][37];     // NMS pass 1, halo 2 (36x36 used), 5328 B
    __shared__ unsigned lcnt, lbase;

    // cbuf aliases sT (dead after phase 4); hm2 aliases hm1 (dead after ph 3)
    unsigned long long* cbuf = (unsigned long long*)&sT[0][0];   // 2 KB < 7 KB
    float (*hm2)[32] = (float(*)[32])&hm1[0][0];                 // 4.6 KB < 5.9 KB

    const int tid = threadIdx.x;     // block is flat 256
    if (tid == 0) lcnt = 0;

    // ---- phase 1: load 40x40 raw scores (halo 4), OOB = -inf --------------
    const bool xedge = (x0 == 0) | (x0 + TX == W);
    if (!xedge) {
        // rows of 10 aligned float4s starting at gx = x0-4
        for (int k = tid; k < 40 * 10; k += 256) {
            int row = k / 10, q = k - row * 10;
            int gy = y0 - 4 + row;
            float4 v;
            if (gy >= 0 && gy < H)
                v = *(const float4*)(sb + (size_t)gy * W + (x0 - 4) + 4 * q);
            else
                v = make_float4(-INFINITY, -INFINITY, -INFINITY, -INFINITY);
            *(float4*)&sT[row][4 * q] = v;
        }
    } else {
        for (int k = tid; k < 40 * 40; k += 256) {
            int row = k / 40, col = k - row * 40;
            int gy = y0 - 4 + row, gx = x0 - 4 + col;
            float v = -INFINITY;
            if (gx >= 0 && gx < W && gy >= 0 && gy < H) v = sb[(size_t)gy * W + gx];
            sT[row][col] = v;
        }
    }
    __syncthreads();

    // ---- phase 2: horizontal 5-max, rows 0..39, cols 0..35 ----------------
    for (int k = tid; k < 40 * 36; k += 256) {
        int r = k / 36, c = k - r * 36;
        float m = sT[r][c];
        m = fmaxf(m, sT[r][c + 1]); m = fmaxf(m, sT[r][c + 2]);
        m = fmaxf(m, sT[r][c + 3]); m = fmaxf(m, sT[r][c + 4]);
        hm1[r][c] = m;
    }
    __syncthreads();

    // ---- phase 3: vertical 5-max + compare  -> NMS pass 1 (36x36, halo 2) -
    for (int k = tid; k < 36 * 36; k += 256) {
        int ly = k / 36, lx = k - ly * 36;
        int gy = y0 - 2 + ly, gx = x0 - 2 + lx;
        float r = -INFINITY;                      // OOB marker = -inf padding
        if (gx >= 0 && gx < W && gy >= 0 && gy < H) {
            float v = sT[ly + 2][lx + 2];
            float m = hm1[ly][lx];
            m = fmaxf(m, hm1[ly + 1][lx]); m = fmaxf(m, hm1[ly + 2][lx]);
            m = fmaxf(m, hm1[ly + 3][lx]); m = fmaxf(m, hm1[ly + 4][lx]);
            r = (v == m) ? v : 0.0f;
        }
        n1[ly][lx] = r;
    }
    __syncthreads();   // sT, hm1 now dead -> cbuf/hm2 aliases valid

    // ---- phase 4: horizontal 5-max of n1, rows 0..35, cols 0..31 ----------
    for (int k = tid; k < 36 * 32; k += 256) {
        int r = k >> 5, c = k & 31;
        float m = n1[r][c];
        m = fmaxf(m, n1[r][c + 1]); m = fmaxf(m, n1[r][c + 2]);
        m = fmaxf(m, n1[r][c + 3]); m = fmaxf(m, n1[r][c + 4]);
        hm2[r][c] = m;
    }
    __syncthreads();

    // ---- phase 5: vertical 5-max + compare -> NMS pass 2, compact to LDS --
    for (int k = tid; k < 32 * 32; k += 256) {
        int ty = k >> 5, tx = k & 31;
        float v = n1[ty + 2][tx + 2];
        float m = hm2[ty][tx];
        m = fmaxf(m, hm2[ty + 1][tx]); m = fmaxf(m, hm2[ty + 2][tx]);
        m = fmaxf(m, hm2[ty + 3][tx]); m = fmaxf(m, hm2[ty + 4][tx]);
        float r = (v == m) ? v : 0.0f;
        if (r > SCORES_TH) {
            unsigned idx = (unsigned)((y0 + ty) * W + (x0 + tx));
            unsigned long long key =
                ((unsigned long long)__float_as_uint(r) << 32) | (unsigned)(~idx);
            unsigned p = atomicAdd(&lcnt, 1u);    // LDS atomic
            if (p < CBUF) cbuf[p] = key;
        }
    }
    __syncthreads();

    // ---- phase 6: one global atomic per block, then coalesced flush -------
    unsigned n = lcnt; if (n > CBUF) n = CBUF;
    if (tid == 0) lbase = atomicAdd(&counts[b * CSTRIDE], n);
    __syncthreads();
    unsigned base = lbase;
    for (unsigned k = tid; k < n; k += 256)
        if (base + k < CAP) cand[(size_t)b * CAP + base + k] = cbuf[k];
}

// ---------------------------------------------------------------------------
// K2: per-batch histogram radix-select: find bucket threshold T so that
// #(bucket >= T) >= 5000 (or select all if fewer), gather selected into sel[].
// ---------------------------------------------------------------------------
__global__ __launch_bounds__(256) void select_thresh(
    const unsigned* __restrict__ counts,
    const unsigned long long* __restrict__ cand,
    unsigned long long* __restrict__ sel,
    unsigned* __restrict__ selC)
{
    const int b = blockIdx.x;
    __shared__ unsigned hist[NB];
    __shared__ int Tsh;
    __shared__ unsigned cnt;
    const int tid = threadIdx.x;

    for (int i = tid; i < NB; i += 256) hist[i] = 0;
    if (tid == 0) cnt = 0;
    __syncthreads();

    unsigned M = counts[b * CSTRIDE]; if (M > CAP) M = CAP;
    const unsigned long long* cb = cand + (size_t)b * CAP;

    for (unsigned i = tid; i < M; i += 256) {
        unsigned bits = (unsigned)(cb[i] >> 32);
        int bk = (int)(bits >> 12) - OFFB;
        bk = bk < 0 ? 0 : (bk >= NB ? NB - 1 : bk);
        atomicAdd(&hist[bk], 1u);
    }
    __syncthreads();

    if (tid == 0) {
        unsigned acc = 0; int T = 0;
        for (int bk = NB - 1; bk >= 0; --bk) {
            acc += hist[bk];
            if (acc >= TOPK) { T = bk; break; }
        }
        Tsh = T;                                  // M < TOPK -> T=0 (select all)
    }
    __syncthreads();
    const int T = Tsh;

    for (unsigned i = tid; i < M; i += 256) {
        unsigned long long key = cb[i];
        unsigned bits = (unsigned)(key >> 32);
        int bk = (int)(bits >> 12) - OFFB;
        bk = bk < 0 ? 0 : (bk >= NB ? NB - 1 : bk);
        if (bk >= T) {
            unsigned p = atomicAdd(&cnt, 1u);
            if (p < SELCAP) sel[(size_t)b * SELCAP + p] = key;
        }
    }
    __syncthreads();
    if (tid == 0) selC[b] = cnt > SELCAP ? SELCAP : cnt;
}

// ---------------------------------------------------------------------------
// K3: exact rank by counting (keys unique -> ranks are a permutation),
// then 5x5 softmax sub-pixel refinement, scatter to out[rank].
// grid (8, B), block 1024.
// ---------------------------------------------------------------------------
__global__ __launch_bounds__(1024) void rank_refine(
    const float* __restrict__ s,
    const unsigned long long* __restrict__ sel,
    const unsigned* __restrict__ selC,
    float* __restrict__ out)
{
    const int b = blockIdx.y;
    const unsigned C = selC[b];
    __shared__ unsigned long long keys[SELCAP];   // 64 KB
    const int tid = threadIdx.x;
    const unsigned long long* sb = sel + (size_t)b * SELCAP;

    for (int i = tid; i < SELCAP; i += 1024)
        keys[i] = (i < (int)C) ? sb[i] : 0ull;
    __syncthreads();

    const unsigned i = blockIdx.x * 1024u + (unsigned)tid;
    if (i >= C) return;

    const unsigned long long my = keys[i];
    unsigned rank = 0;
    for (unsigned j = 0; j < C; ++j)              // LDS broadcast reads
        rank += (keys[j] > my) ? 1u : 0u;
    if (rank >= TOPK) return;

    float v = __uint_as_float((unsigned)(my >> 32));
    unsigned idx = ~((unsigned)my);
    int y = (int)(idx >> 10), x = (int)(idx & 1023);

    const float* smb = s + (size_t)b * (H * W);
    float wsum = 0.f, ox = 0.f, oy = 0.f;
    #pragma unroll
    for (int dy = -2; dy <= 2; ++dy) {
        #pragma unroll
        for (int dx = -2; dx <= 2; ++dx) {
            int yy = y + dy, xx = x + dx;
            bool inb = (yy >= 0 && yy < H && xx >= 0 && xx < W);
            int yc = min(max(yy, 0), H - 1), xc = min(max(xx, 0), W - 1);
            float p = smb[yc * W + xc];
            float lg = inb ? p * 10.0f : -1e9f;   // 1/TEMPERATURE = 10
            float e = expf(lg);                   // exp(-1e9) underflows to 0
            wsum += e; ox += e * (float)dx; oy += e * (float)dy;
        }
    }
    float offx = ox / wsum, offy = oy / wsum;
    out[((size_t)b * TOPK + rank) * 2 + 0] = (float)x + offx;
    out[((size_t)b * TOPK + rank) * 2 + 1] = (float)y + offy;
    out[(size_t)B * TOPK * 2 + (size_t)b * TOPK + rank] = v;
}

// ---------------------------------------------------------------------------
extern "C" void kernel_launch(void* const* d_in, const int* in_sizes, int n_in,
                              void* d_out, int out_size, void* d_ws, size_t ws_size,
                              hipStream_t stream)
{
    const float* s = (const float*)d_in[0];
    float* out = (float*)d_out;
    char* ws = (char*)d_ws;

    unsigned* counts            = (unsigned*)ws;                              // 16*32*4 = 2 KB
    unsigned* selC              = (unsigned*)(ws + 2048);                     // 64 B
    unsigned long long* sel     = (unsigned long long*)(ws + 2048 + 64);      // 1 MB
    unsigned long long* cand    = (unsigned long long*)(ws + 2048 + 64 + (size_t)B * SELCAP * 8); // 8 MB

    hipMemsetAsync(counts, 0, B * CSTRIDE * sizeof(unsigned), stream);
    hipMemsetAsync(d_out, 0, (size_t)out_size * sizeof(float), stream);

    nms_compact<<<dim3(W / TX, H / TY, B), dim3(256), 0, stream>>>(s, counts, cand);
    select_thresh<<<dim3(B), dim3(256), 0, stream>>>(counts, cand, sel, selC);
    rank_refine<<<dim3(SELCAP / 1024, B), dim3(1024), 0, stream>>>(s, sel, selC, out);
}

// Round 8
// 238.755 us; speedup vs baseline: 12.9018x; 1.3472x over previous
//
#include <hip/hip_runtime.h>
#include <math.h>

// Problem constants
#define B 16
#define H 1024
#define W 1024
#define TOPK 5000
#define SCORES_TH 0.2f

// workspace layout
#define CAP 65536          // max candidates per batch (expected ~42k)
#define SELCAP 8192        // max selected (threshold-passing) per batch
#define NB 4928            // histogram buckets over value bits[31:12]
#define OFFB 0x3E4CC       // (bits(0.2f) >> 12)
#define CSTRIDE 32         // counts padded 32 uints = 128 B apart (cacheline)
#define GSTRIDE 4932       // per-batch stride of G (NB+1 used, padded)

#define TX 32              // 32x32 output tile per block, 256 threads
#define TY 32
#define CBUF 256           // per-block candidate cap (expected ~41)

// ---------------------------------------------------------------------------
// K1: fused double 5x5 NMS (separable max) + block-aggregated compaction.
// Keys: (value_bits << 32) | ~idx  (desc value, asc index) — unique per pixel.
// ---------------------------------------------------------------------------
__global__ __launch_bounds__(256) void nms_compact(
    const float* __restrict__ s,
    unsigned* __restrict__ counts,
    unsigned long long* __restrict__ cand)
{
    const int b  = blockIdx.z;
    const int x0 = blockIdx.x * TX;
    const int y0 = blockIdx.y * TY;
    const float* sb = s + (size_t)b * (H * W);

    __shared__ float sT[40][44];     // raw tile + halo 4 (40x40 used)
    __shared__ float hm1[40][37];    // horizontal 5-max (40x36 used)
    __shared__ float n1[36][37];     // NMS pass 1, halo 2 (36x36 used)
    __shared__ unsigned lcnt, lbase;

    unsigned long long* cbuf = (unsigned long long*)&sT[0][0];   // alias, 2 KB
    float (*hm2)[32] = (float(*)[32])&hm1[0][0];                 // alias

    const int tid = threadIdx.x;
    if (tid == 0) lcnt = 0;

    // ---- phase 1: load 40x40 raw scores (halo 4), OOB = -inf --------------
    const bool xedge = (x0 == 0) | (x0 + TX == W);
    if (!xedge) {
        for (int k = tid; k < 40 * 10; k += 256) {
            int row = k / 10, q = k - row * 10;
            int gy = y0 - 4 + row;
            float4 v;
            if (gy >= 0 && gy < H)
                v = *(const float4*)(sb + (size_t)gy * W + (x0 - 4) + 4 * q);
            else
                v = make_float4(-INFINITY, -INFINITY, -INFINITY, -INFINITY);
            *(float4*)&sT[row][4 * q] = v;
        }
    } else {
        for (int k = tid; k < 40 * 40; k += 256) {
            int row = k / 40, col = k - row * 40;
            int gy = y0 - 4 + row, gx = x0 - 4 + col;
            float v = -INFINITY;
            if (gx >= 0 && gx < W && gy >= 0 && gy < H) v = sb[(size_t)gy * W + gx];
            sT[row][col] = v;
        }
    }
    __syncthreads();

    // ---- phase 2: horizontal 5-max ----------------------------------------
    for (int k = tid; k < 40 * 36; k += 256) {
        int r = k / 36, c = k - r * 36;
        float m = sT[r][c];
        m = fmaxf(m, sT[r][c + 1]); m = fmaxf(m, sT[r][c + 2]);
        m = fmaxf(m, sT[r][c + 3]); m = fmaxf(m, sT[r][c + 4]);
        hm1[r][c] = m;
    }
    __syncthreads();

    // ---- phase 3: vertical 5-max + compare -> NMS pass 1 ------------------
    for (int k = tid; k < 36 * 36; k += 256) {
        int ly = k / 36, lx = k - ly * 36;
        int gy = y0 - 2 + ly, gx = x0 - 2 + lx;
        float r = -INFINITY;
        if (gx >= 0 && gx < W && gy >= 0 && gy < H) {
            float v = sT[ly + 2][lx + 2];
            float m = hm1[ly][lx];
            m = fmaxf(m, hm1[ly + 1][lx]); m = fmaxf(m, hm1[ly + 2][lx]);
            m = fmaxf(m, hm1[ly + 3][lx]); m = fmaxf(m, hm1[ly + 4][lx]);
            r = (v == m) ? v : 0.0f;
        }
        n1[ly][lx] = r;
    }
    __syncthreads();   // sT, hm1 dead -> aliases valid

    // ---- phase 4: horizontal 5-max of n1 ----------------------------------
    for (int k = tid; k < 36 * 32; k += 256) {
        int r = k >> 5, c = k & 31;
        float m = n1[r][c];
        m = fmaxf(m, n1[r][c + 1]); m = fmaxf(m, n1[r][c + 2]);
        m = fmaxf(m, n1[r][c + 3]); m = fmaxf(m, n1[r][c + 4]);
        hm2[r][c] = m;
    }
    __syncthreads();

    // ---- phase 5: vertical 5-max + compare -> NMS pass 2, compact ---------
    for (int k = tid; k < 32 * 32; k += 256) {
        int ty = k >> 5, tx = k & 31;
        float v = n1[ty + 2][tx + 2];
        float m = hm2[ty][tx];
        m = fmaxf(m, hm2[ty + 1][tx]); m = fmaxf(m, hm2[ty + 2][tx]);
        m = fmaxf(m, hm2[ty + 3][tx]); m = fmaxf(m, hm2[ty + 4][tx]);
        float r = (v == m) ? v : 0.0f;
        if (r > SCORES_TH) {
            unsigned idx = (unsigned)((y0 + ty) * W + (x0 + tx));
            unsigned long long key =
                ((unsigned long long)__float_as_uint(r) << 32) | (unsigned)(~idx);
            unsigned p = atomicAdd(&lcnt, 1u);
            if (p < CBUF) cbuf[p] = key;
        }
    }
    __syncthreads();

    // ---- phase 6: one global atomic per block, coalesced flush ------------
    unsigned n = lcnt; if (n > CBUF) n = CBUF;
    if (tid == 0) lbase = atomicAdd(&counts[b * CSTRIDE], n);
    __syncthreads();
    unsigned base = lbase;
    for (unsigned k = tid; k < n; k += 256)
        if (base + k < CAP) cand[(size_t)b * CAP + base + k] = cbuf[k];
}

// ---------------------------------------------------------------------------
// K2: histogram -> block-wide suffix-sum scan -> threshold T -> bucket-grouped
// scatter. G[b][bk] = #{keys in buckets >= bk} (G[b][NB] = 0) enables O(1)
// segment lookup in K3. One block per batch.
// ---------------------------------------------------------------------------
__global__ __launch_bounds__(256) void select_thresh(
    const unsigned* __restrict__ counts,
    const unsigned long long* __restrict__ cand,
    unsigned long long* __restrict__ sel,
    unsigned* __restrict__ selC,
    unsigned* __restrict__ G)
{
    const int b = blockIdx.x;
    __shared__ unsigned I[NB + 1];     // hist -> inclusive suffix sum
    __shared__ unsigned csum[256];
    __shared__ int Tsh;
    const int tid = threadIdx.x;

    for (int i = tid; i < NB + 1; i += 256) I[i] = 0;
    if (tid == 0) Tsh = 0;
    __syncthreads();

    unsigned M = counts[b * CSTRIDE]; if (M > CAP) M = CAP;
    const unsigned long long* cb = cand + (size_t)b * CAP;

    // histogram
    for (unsigned i = tid; i < M; i += 256) {
        unsigned bits = (unsigned)(cb[i] >> 32);
        int bk = (int)(bits >> 12) - OFFB;
        bk = bk < 0 ? 0 : (bk >= NB ? NB - 1 : bk);
        atomicAdd(&I[bk], 1u);
    }
    __syncthreads();

    // block-wide suffix-sum (descending bk); r = NB-1-bk ascending, chunk=20
    unsigned local = 0;
    #pragma unroll
    for (int u = 0; u < 20; ++u) {
        int r = tid * 20 + u;
        if (r < NB) local += I[NB - 1 - r];
    }
    csum[tid] = local;
    __syncthreads();
    for (int off = 1; off < 256; off <<= 1) {       // Hillis-Steele inclusive
        unsigned v = (tid >= off) ? csum[tid - off] : 0u;
        __syncthreads();
        csum[tid] += v;
        __syncthreads();
    }
    unsigned run = (tid == 0) ? 0u : csum[tid - 1];
    #pragma unroll
    for (int u = 0; u < 20; ++u) {
        int r = tid * 20 + u;
        if (r < NB) {
            int bk = NB - 1 - r;
            run += I[bk];          // read own chunk element, then overwrite
            I[bk] = run;           // I becomes inclusive suffix sum
        }
    }
    __syncthreads();

    // T = max bk with I[bk] >= TOPK  (0 if total < TOPK -> select all)
    int localT = -1;
    #pragma unroll
    for (int u = 0; u < 20; ++u) {
        int r = tid * 20 + u;
        if (r < NB) {
            int bk = NB - 1 - r;
            if (I[bk] >= TOPK && bk > localT) localT = bk;
        }
    }
    if (localT >= 0) atomicMax(&Tsh, localT);
    __syncthreads();
    const int T = Tsh;
    if (tid == 0) selC[b] = I[T];

    // publish G (segment table) BEFORE gather mutates I
    unsigned* Gb = G + (size_t)b * GSTRIDE;
    for (int i = tid; i < NB + 1; i += 256) Gb[i] = I[i];
    __syncthreads();

    // bucket-grouped scatter: cursor of bucket bk is I[bk+1] (segment start)
    for (unsigned i = tid; i < M; i += 256) {
        unsigned long long key = cb[i];
        unsigned bits = (unsigned)(key >> 32);
        int bk = (int)(bits >> 12) - OFFB;
        bk = bk < 0 ? 0 : (bk >= NB ? NB - 1 : bk);
        if (bk >= T) {
            unsigned p = atomicAdd(&I[bk + 1], 1u);
            if (p < SELCAP) sel[(size_t)b * SELCAP + p] = key;
        }
    }
}

// ---------------------------------------------------------------------------
// K3: two-level exact rank: rank = G[bk+1] + #{same-bucket keys > mine}
// (keys unique -> exact permutation), then 5x5 softmax refinement, scatter.
// grid (SELCAP/256, B), block 256. No LDS -> full occupancy.
// ---------------------------------------------------------------------------
__global__ __launch_bounds__(256) void rank_refine(
    const float* __restrict__ s,
    const unsigned long long* __restrict__ sel,
    const unsigned* __restrict__ selC,
    const unsigned* __restrict__ G,
    float* __restrict__ out)
{
    const int b = blockIdx.y;
    const unsigned C = selC[b];
    const unsigned i = blockIdx.x * 256u + threadIdx.x;
    if (i >= C) return;

    const unsigned long long* sb = sel + (size_t)b * SELCAP;
    const unsigned long long my = sb[i];
    unsigned bits = (unsigned)(my >> 32);
    int bk = (int)(bits >> 12) - OFFB;
    bk = bk < 0 ? 0 : (bk >= NB ? NB - 1 : bk);

    const unsigned* Gb = G + (size_t)b * GSTRIDE;
    const unsigned start = Gb[bk + 1], end = Gb[bk];   // my bucket's segment
    unsigned rank = start;
    for (unsigned j = start; j < end; ++j)
        rank += (sb[j] > my) ? 1u : 0u;
    if (rank >= TOPK) return;

    float v = __uint_as_float(bits);
    unsigned idx = ~((unsigned)my);
    int y = (int)(idx >> 10), x = (int)(idx & 1023);

    const float* smb = s + (size_t)b * (H * W);
    float wsum = 0.f, ox = 0.f, oy = 0.f;
    #pragma unroll
    for (int dy = -2; dy <= 2; ++dy) {
        #pragma unroll
        for (int dx = -2; dx <= 2; ++dx) {
            int yy = y + dy, xx = x + dx;
            bool inb = (yy >= 0 && yy < H && xx >= 0 && xx < W);
            int yc = min(max(yy, 0), H - 1), xc = min(max(xx, 0), W - 1);
            float p = smb[yc * W + xc];
            float lg = inb ? p * 10.0f : -1e9f;   // 1/TEMPERATURE = 10
            float e = expf(lg);
            wsum += e; ox += e * (float)dx; oy += e * (float)dy;
        }
    }
    float offx = ox / wsum, offy = oy / wsum;
    out[((size_t)b * TOPK + rank) * 2 + 0] = (float)x + offx;
    out[((size_t)b * TOPK + rank) * 2 + 1] = (float)y + offy;
    out[(size_t)B * TOPK * 2 + (size_t)b * TOPK + rank] = v;
}

// ---------------------------------------------------------------------------
extern "C" void kernel_launch(void* const* d_in, const int* in_sizes, int n_in,
                              void* d_out, int out_size, void* d_ws, size_t ws_size,
                              hipStream_t stream)
{
    const float* s = (const float*)d_in[0];
    float* out = (float*)d_out;
    char* ws = (char*)d_ws;

    size_t off = 0;
    unsigned* counts        = (unsigned*)(ws + off);  off += 2048;                       // B*CSTRIDE*4
    unsigned* selC          = (unsigned*)(ws + off);  off += 64;
    unsigned* G             = (unsigned*)(ws + off);  off += (size_t)B * GSTRIDE * 4;    // ~316 KB
    unsigned long long* sel = (unsigned long long*)(ws + off); off += (size_t)B * SELCAP * 8;  // 1 MB
    unsigned long long* cand= (unsigned long long*)(ws + off);                           // 8 MB

    hipMemsetAsync(counts, 0, 2048, stream);
    hipMemsetAsync(d_out, 0, (size_t)out_size * sizeof(float), stream);

    nms_compact<<<dim3(W / TX, H / TY, B), dim3(256), 0, stream>>>(s, counts, cand);
    select_thresh<<<dim3(B), dim3(256), 0, stream>>>(counts, cand, sel, selC, G);
    rank_refine<<<dim3(SELCAP / 256, B), dim3(256), 0, stream>>>(s, sel, selC, G, out);
}

// Round 9
// 166.119 us; speedup vs baseline: 18.5432x; 1.4373x over previous
//
#include <hip/hip_runtime.h>
#include <math.h>

// Problem constants
#define B 16
#define H 1024
#define W 1024
#define TOPK 5000
#define SCORES_TH 0.2f

// workspace layout
#define CAP 65536          // max candidates per batch (expected ~33k)
#define SELCAP 8192        // max selected per batch
#define NB 4928            // histogram buckets over value bits[31:12]
#define OFFB 0x3E4CC       // (bits(0.2f) >> 12)
#define CSTRIDE 32         // counts padded 128 B apart
#define GSTRIDE 4932       // per-batch stride of G (NB+1 used)

#define CBUF 256           // per-tile candidate cap (expected ~33)

__device__ __forceinline__ float4 fmax4(float4 a, float4 b) {
    return make_float4(fmaxf(a.x, b.x), fmaxf(a.y, b.y),
                       fmaxf(a.z, b.z), fmaxf(a.w, b.w));
}

// ---------------------------------------------------------------------------
// K1: fused double 5x5 NMS. Pass 1 dense (separable, float4 LDS ops);
// pass 2 sparse (survivor list + strict-dominance test, exactly equivalent
// to n1 == maxpool5x5(n1) since survivors are ~1/25 dense).
// Keys: (value_bits << 32) | ~idx  (desc value, asc index) — unique per pixel.
// ---------------------------------------------------------------------------
__global__ __launch_bounds__(256) void nms_compact(
    const float* __restrict__ s,
    unsigned* __restrict__ counts,
    unsigned long long* __restrict__ cand)
{
    const int b = blockIdx.z;
    // XCD swizzle: dispatch id % 8 = XCD. Give each XCD a contiguous
    // 4-tile-row stripe, row-major within -> halo re-reads hit same L2.
    const int lin = blockIdx.y * 32 + blockIdx.x;
    const int xcd = lin & 7, seq = lin >> 3;
    const int x0 = (seq & 31) * 32;
    const int y0 = (xcd * 4 + (seq >> 5)) * 32;
    const float* sb = s + (size_t)b * (H * W);

    __shared__ float sT[40][44];     // raw tile + halo 4, 7040 B (stride 16B-aligned)
    __shared__ float hm1[40][36];    // horizontal 5-max, 5760 B
    __shared__ float n1[36][36];     // NMS pass 1 (halo 2), 5184 B
    __shared__ unsigned slist[256];  // pass-1 survivor positions (ty<<5|tx)
    __shared__ unsigned lcnt, scnt, lbase;

    unsigned long long* cbuf = (unsigned long long*)&sT[0][0];  // sT dead after ph3

    const int tid = threadIdx.x;
    if (tid == 0) { lcnt = 0; scnt = 0; }

    // ---- phase 1: load 40x40 raw scores (halo 4), OOB = -inf --------------
    const bool xedge = (x0 == 0) | (x0 + 32 == W);
    if (!xedge) {
        for (int k = tid; k < 40 * 10; k += 256) {
            int row = k / 10, q = k - row * 10;
            int gy = y0 - 4 + row;
            float4 v;
            if (gy >= 0 && gy < H)
                v = *(const float4*)(sb + (size_t)gy * W + (x0 - 4) + 4 * q);
            else
                v = make_float4(-INFINITY, -INFINITY, -INFINITY, -INFINITY);
            *(float4*)&sT[row][4 * q] = v;
        }
    } else {
        for (int k = tid; k < 40 * 40; k += 256) {
            int row = k / 40, col = k - row * 40;
            int gy = y0 - 4 + row, gx = x0 - 4 + col;
            float v = -INFINITY;
            if (gx >= 0 && gx < W && gy >= 0 && gy < H) v = sb[(size_t)gy * W + gx];
            sT[row][col] = v;
        }
    }
    __syncthreads();

    // ---- phase 2: horizontal 5-max (float4): hm1[r][c]=max(sT[r][c..c+4]) --
    for (int k = tid; k < 40 * 9; k += 256) {
        int r = k / 9, c4 = (k - r * 9) * 4;
        float4 a = *(float4*)&sT[r][c4];
        float4 bq = *(float4*)&sT[r][c4 + 4];
        float m0 = fmaxf(a.x, a.y), m1 = fmaxf(a.y, a.z), m2 = fmaxf(a.z, a.w);
        float m3 = fmaxf(a.w, bq.x), m4 = fmaxf(bq.x, bq.y), m5 = fmaxf(bq.y, bq.z);
        float q0 = fmaxf(m0, m2), q1 = fmaxf(m1, m3), q2 = fmaxf(m2, m4), q3 = fmaxf(m3, m5);
        float4 o = make_float4(fmaxf(q0, bq.x), fmaxf(q1, bq.y),
                               fmaxf(q2, bq.z), fmaxf(q3, bq.w));
        *(float4*)&hm1[r][c4] = o;
    }
    __syncthreads();

    // ---- phase 3: vertical 5-max + compare -> n1 (36x36, halo 2) ----------
    for (int k = tid; k < 36 * 9; k += 256) {
        int ly = k / 9, lx4 = (k - ly * 9) * 4;
        float4 m = *(float4*)&hm1[ly][lx4];
        m = fmax4(m, *(float4*)&hm1[ly + 1][lx4]);
        m = fmax4(m, *(float4*)&hm1[ly + 2][lx4]);
        m = fmax4(m, *(float4*)&hm1[ly + 3][lx4]);
        m = fmax4(m, *(float4*)&hm1[ly + 4][lx4]);
        float2 c01 = *(float2*)&sT[ly + 2][lx4 + 2];
        float2 c23 = *(float2*)&sT[ly + 2][lx4 + 4];
        int gy = y0 - 2 + ly;
        int gxb = x0 - 2 + lx4;
        bool yin = (gy >= 0) & (gy < H);
        float4 o;
        o.x = (yin && gxb + 0 >= 0 && gxb + 0 < W) ? ((c01.x == m.x) ? c01.x : 0.0f) : -INFINITY;
        o.y = (yin && gxb + 1 >= 0 && gxb + 1 < W) ? ((c01.y == m.y) ? c01.y : 0.0f) : -INFINITY;
        o.z = (yin && gxb + 2 >= 0 && gxb + 2 < W) ? ((c23.x == m.z) ? c23.x : 0.0f) : -INFINITY;
        o.w = (yin && gxb + 3 >= 0 && gxb + 3 < W) ? ((c23.y == m.w) ? c23.y : 0.0f) : -INFINITY;
        *(float4*)&n1[ly][lx4] = o;
    }
    __syncthreads();   // sT dead -> cbuf alias valid

    // ---- phase 3.5: collect pass-1 survivors (> TH) in 32x32 core ---------
    for (int k = tid; k < 32 * 8; k += 256) {
        int ty = k >> 3, tx4 = (k & 7) * 4;
        float2 a01 = *(float2*)&n1[ty + 2][tx4 + 2];
        float2 a23 = *(float2*)&n1[ty + 2][tx4 + 4];
        float v[4] = { a01.x, a01.y, a23.x, a23.y };
        #pragma unroll
        for (int i = 0; i < 4; ++i) {
            if (v[i] > SCORES_TH) {
                unsigned p = atomicAdd(&scnt, 1u);
                if (p < 256) slist[p] = (unsigned)((ty << 5) | (tx4 + i));
            }
        }
    }
    __syncthreads();

    // ---- phase 4: strict-dominance test (== NMS pass 2), emit keys --------
    unsigned ns = scnt; if (ns > 256) ns = 256;
    if (tid < (int)ns) {
        unsigned e = slist[tid];
        int ty = (int)(e >> 5) & 31, tx = (int)(e & 31);
        float v = n1[ty + 2][tx + 2];
        bool dom = false;
        #pragma unroll
        for (int dy = 0; dy < 5; ++dy) {
            dom = dom | (n1[ty + dy][tx + 0] > v) | (n1[ty + dy][tx + 1] > v)
                      | (n1[ty + dy][tx + 2] > v) | (n1[ty + dy][tx + 3] > v)
                      | (n1[ty + dy][tx + 4] > v);
        }
        if (!dom) {
            unsigned idx = (unsigned)((y0 + ty) * W + (x0 + tx));
            unsigned long long key =
                ((unsigned long long)__float_as_uint(v) << 32) | (unsigned)(~idx);
            unsigned p = atomicAdd(&lcnt, 1u);
            if (p < CBUF) cbuf[p] = key;
        }
    }
    __syncthreads();

    // ---- phase 5: one global atomic per block, coalesced flush ------------
    unsigned n = lcnt; if (n > CBUF) n = CBUF;
    if (tid == 0) lbase = atomicAdd(&counts[b * CSTRIDE], n);
    __syncthreads();
    unsigned base = lbase;
    for (unsigned k = tid; k < n; k += 256)
        if (base + k < CAP) cand[(size_t)b * CAP + base + k] = cbuf[k];
}

// ---------------------------------------------------------------------------
// K2: histogram -> suffix-sum scan -> threshold T -> bucket-grouped scatter.
// G[b][bk] = #{keys in buckets >= bk}. 1024 threads/block, one block/batch.
// ---------------------------------------------------------------------------
__global__ __launch_bounds__(1024) void select_thresh(
    const unsigned* __restrict__ counts,
    const unsigned long long* __restrict__ cand,
    unsigned long long* __restrict__ sel,
    unsigned* __restrict__ selC,
    unsigned* __restrict__ G)
{
    const int b = blockIdx.x;
    __shared__ unsigned I[NB + 1];
    __shared__ unsigned csum[1024];
    __shared__ int Tsh;
    const int tid = threadIdx.x;

    for (int i = tid; i < NB + 1; i += 1024) I[i] = 0;
    if (tid == 0) Tsh = 0;
    __syncthreads();

    unsigned M = counts[b * CSTRIDE]; if (M > CAP) M = CAP;
    const unsigned long long* cb = cand + (size_t)b * CAP;

    for (unsigned i = tid; i < M; i += 1024) {
        unsigned bits = (unsigned)(cb[i] >> 32);
        int bk = (int)(bits >> 12) - OFFB;
        bk = bk < 0 ? 0 : (bk >= NB ? NB - 1 : bk);
        atomicAdd(&I[bk], 1u);
    }
    __syncthreads();

    // suffix-sum over descending bk; r = NB-1-bk, chunk of 5 per thread
    unsigned local = 0;
    #pragma unroll
    for (int u = 0; u < 5; ++u) {
        int r = tid * 5 + u;
        if (r < NB) local += I[NB - 1 - r];
    }
    csum[tid] = local;
    __syncthreads();
    for (int off = 1; off < 1024; off <<= 1) {      // Hillis-Steele inclusive
        unsigned v = (tid >= off) ? csum[tid - off] : 0u;
        __syncthreads();
        csum[tid] += v;
        __syncthreads();
    }
    unsigned run = (tid == 0) ? 0u : csum[tid - 1];
    #pragma unroll
    for (int u = 0; u < 5; ++u) {
        int r = tid * 5 + u;
        if (r < NB) {
            int bk = NB - 1 - r;
            run += I[bk];
            I[bk] = run;          // I becomes inclusive suffix sum
        }
    }
    __syncthreads();

    // T = max bk with I[bk] >= TOPK (0 if total < TOPK -> select all)
    int localT = -1;
    #pragma unroll
    for (int u = 0; u < 5; ++u) {
        int r = tid * 5 + u;
        if (r < NB) {
            int bk = NB - 1 - r;
            if (I[bk] >= TOPK && bk > localT) localT = bk;
        }
    }
    if (localT >= 0) atomicMax(&Tsh, localT);
    __syncthreads();
    const int T = Tsh;
    if (tid == 0) selC[b] = I[T];

    // publish segment table G before gather mutates I
    unsigned* Gb = G + (size_t)b * GSTRIDE;
    for (int i = tid; i < NB + 1; i += 1024) Gb[i] = I[i];
    __syncthreads();

    // bucket-grouped scatter: cursor of bucket bk is I[bk+1] (segment start)
    for (unsigned i = tid; i < M; i += 1024) {
        unsigned long long key = cb[i];
        unsigned bits = (unsigned)(key >> 32);
        int bk = (int)(bits >> 12) - OFFB;
        bk = bk < 0 ? 0 : (bk >= NB ? NB - 1 : bk);
        if (bk >= T) {
            unsigned p = atomicAdd(&I[bk + 1], 1u);
            if (p < SELCAP) sel[(size_t)b * SELCAP + p] = key;
        }
    }
}

// ---------------------------------------------------------------------------
// K3: two-level exact rank: rank = G[bk+1] + #{same-bucket keys > mine},
// then 5x5 softmax refinement, scatter to out[rank]. No LDS.
// ---------------------------------------------------------------------------
__global__ __launch_bounds__(256) void rank_refine(
    const float* __restrict__ s,
    const unsigned long long* __restrict__ sel,
    const unsigned* __restrict__ selC,
    const unsigned* __restrict__ G,
    float* __restrict__ out)
{
    const int b = blockIdx.y;
    const unsigned C = selC[b];
    const unsigned i = blockIdx.x * 256u + threadIdx.x;
    if (i >= C) return;

    const unsigned long long* sb = sel + (size_t)b * SELCAP;
    const unsigned long long my = sb[i];
    unsigned bits = (unsigned)(my >> 32);
    int bk = (int)(bits >> 12) - OFFB;
    bk = bk < 0 ? 0 : (bk >= NB ? NB - 1 : bk);

    const unsigned* Gb = G + (size_t)b * GSTRIDE;
    const unsigned start = Gb[bk + 1], end = Gb[bk];
    unsigned rank = start;
    for (unsigned j = start; j < end; ++j)
        rank += (sb[j] > my) ? 1u : 0u;
    if (rank >= TOPK) return;

    float v = __uint_as_float(bits);
    unsigned idx = ~((unsigned)my);
    int y = (int)(idx >> 10), x = (int)(idx & 1023);

    const float* smb = s + (size_t)b * (H * W);
    float wsum = 0.f, ox = 0.f, oy = 0.f;
    #pragma unroll
    for (int dy = -2; dy <= 2; ++dy) {
        #pragma unroll
        for (int dx = -2; dx <= 2; ++dx) {
            int yy = y + dy, xx = x + dx;
            bool inb = (yy >= 0 && yy < H && xx >= 0 && xx < W);
            int yc = min(max(yy, 0), H - 1), xc = min(max(xx, 0), W - 1);
            float p = smb[yc * W + xc];
            float lg = inb ? p * 10.0f : -1e9f;   // 1/TEMPERATURE = 10
            float e = expf(lg);
            wsum += e; ox += e * (float)dx; oy += e * (float)dy;
        }
    }
    float offx = ox / wsum, offy = oy / wsum;
    out[((size_t)b * TOPK + rank) * 2 + 0] = (float)x + offx;
    out[((size_t)b * TOPK + rank) * 2 + 1] = (float)y + offy;
    out[(size_t)B * TOPK * 2 + (size_t)b * TOPK + rank] = v;
}

// ---------------------------------------------------------------------------
extern "C" void kernel_launch(void* const* d_in, const int* in_sizes, int n_in,
                              void* d_out, int out_size, void* d_ws, size_t ws_size,
                              hipStream_t stream)
{
    const float* s = (const float*)d_in[0];
    float* out = (float*)d_out;
    char* ws = (char*)d_ws;

    size_t off = 0;
    unsigned* counts        = (unsigned*)(ws + off);  off += 2048;
    unsigned* selC          = (unsigned*)(ws + off);  off += 64;
    unsigned* G             = (unsigned*)(ws + off);  off += (size_t)B * GSTRIDE * 4;
    unsigned long long* sel = (unsigned long long*)(ws + off); off += (size_t)B * SELCAP * 8;
    unsigned long long* cand= (unsigned long long*)(ws + off);

    hipMemsetAsync(counts, 0, 2048, stream);
    hipMemsetAsync(d_out, 0, (size_t)out_size * sizeof(float), stream);

    nms_compact<<<dim3(32, 32, B), dim3(256), 0, stream>>>(s, counts, cand);
    select_thresh<<<dim3(B), dim3(1024), 0, stream>>>(counts, cand, sel, selC, G);
    rank_refine<<<dim3(SELCAP / 256, B), dim3(256), 0, stream>>>(s, sel, selC, G, out);
}

// Round 10
// 155.125 us; speedup vs baseline: 19.8574x; 1.0709x over previous
//
#include <hip/hip_runtime.h>
#include <math.h>

// Problem constants
#define B 16
#define H 1024
#define W 1024
#define TOPK 5000
#define SCORES_TH 0.2f

// workspace layout
#define CAP 65536          // max candidates per batch (expected ~33k)
#define SELCAP 8192        // max selected per batch
#define NB 4928            // histogram buckets over value bits[31:12]
#define OFFB 0x3E4CC       // (bits(0.2f) >> 12)
#define CSTRIDE 32         // counts padded 128 B apart
#define GSTRIDE 4932       // per-batch stride of G (NB+1 used)

#define CBUF 256           // per-tile candidate cap (expected ~41)

__device__ __forceinline__ float4 fmax4(float4 a, float4 b) {
    return make_float4(fmaxf(a.x, b.x), fmaxf(a.y, b.y),
                       fmaxf(a.z, b.z), fmaxf(a.w, b.w));
}

// ---------------------------------------------------------------------------
// K1: single 5x5 NMS (== double NMS: two pass-1 peaks within Chebyshev-2 see
// each other's windows -> equal values -> both survive pass 2; different-value
// peaks are >=3 apart -> invisible to pass 2. So pass 2 is the identity.)
// Separable vertical-then-horizontal max, all LDS ops aligned b128/b64.
// Keys: (value_bits << 32) | ~idx  (desc value, asc index) — unique per pixel.
// ---------------------------------------------------------------------------
__global__ __launch_bounds__(256) void nms_compact(
    const float* __restrict__ s,
    unsigned* __restrict__ counts,
    unsigned long long* __restrict__ cand)
{
    const int b = blockIdx.z;
    // XCD swizzle: dispatch id % 8 = XCD; each XCD gets a contiguous
    // 4-tile-row stripe so halo re-reads hit the same L2.
    const int lin = blockIdx.y * 32 + blockIdx.x;
    const int xcd = lin & 7, seq = lin >> 3;
    const int x0 = (seq & 31) * 32;
    const int y0 = (xcd * 4 + (seq >> 5)) * 32;
    const float* sb = s + (size_t)b * (H * W);

    __shared__ float sT[36][44];     // rows gy=y0-2..y0+33, cols gx=x0-4..x0+35
    __shared__ float vm[32][44];     // vm[ty][c] = max over sT[ty..ty+4][c]
    __shared__ unsigned long long cbuf[CBUF];
    __shared__ unsigned lcnt, lbase;

    const int tid = threadIdx.x;
    if (tid == 0) lcnt = 0;

    // ---- P1: load 36x40 raw scores (x halo 4 for alignment, y halo 2) -----
    const bool xedge = (x0 == 0) | (x0 + 32 == W);
    if (!xedge) {
        for (int k = tid; k < 36 * 10; k += 256) {
            int row = k / 10, q = k - row * 10;
            int gy = y0 - 2 + row;
            float4 v;
            if (gy >= 0 && gy < H)
                v = *(const float4*)(sb + (size_t)gy * W + (x0 - 4) + 4 * q);
            else
                v = make_float4(-INFINITY, -INFINITY, -INFINITY, -INFINITY);
            *(float4*)&sT[row][4 * q] = v;
        }
    } else {
        for (int k = tid; k < 36 * 40; k += 256) {
            int row = k / 40, col = k - row * 40;
            int gy = y0 - 2 + row, gx = x0 - 4 + col;
            float v = -INFINITY;
            if (gx >= 0 && gx < W && gy >= 0 && gy < H) v = sb[(size_t)gy * W + gx];
            sT[row][col] = v;
        }
    }
    __syncthreads();

    // ---- P2: vertical sliding 5-max, 2 rows/thread (6 reads -> 2 writes) --
    if (tid < 160) {                 // 16 row-groups x 10 col-quads
        int g = tid / 10, q = tid - g * 10;
        int r0 = g * 2, c4 = q * 4;
        float4 s0 = *(float4*)&sT[r0 + 0][c4];
        float4 s1 = *(float4*)&sT[r0 + 1][c4];
        float4 s2 = *(float4*)&sT[r0 + 2][c4];
        float4 s3 = *(float4*)&sT[r0 + 3][c4];
        float4 s4 = *(float4*)&sT[r0 + 4][c4];
        float4 s5 = *(float4*)&sT[r0 + 5][c4];
        float4 p01 = fmax4(s0, s1), p23 = fmax4(s2, s3), p45 = fmax4(s4, s5);
        float4 v0 = fmax4(fmax4(p01, p23), s4);   // max(s0..s4)
        float4 v1 = fmax4(fmax4(p23, p45), s1);   // max(s1..s5)
        *(float4*)&vm[r0 + 0][c4] = v0;
        *(float4*)&vm[r0 + 1][c4] = v1;
    }
    __syncthreads();

    // ---- P3: horizontal 5-max in registers + peak test + emit -------------
    {
        int ty = tid >> 3, tx4 = (tid & 7) * 4;
        float2 va = *(float2*)&vm[ty][tx4 + 2];
        float4 vb = *(float4*)&vm[ty][tx4 + 4];
        float2 vc = *(float2*)&vm[ty][tx4 + 8];
        float a0 = va.x, a1 = va.y, a2 = vb.x, a3 = vb.y,
              a4 = vb.z, a5 = vb.w, a6 = vc.x, a7 = vc.y;
        float p01 = fmaxf(a0, a1), p12 = fmaxf(a1, a2), p23 = fmaxf(a2, a3),
              p34 = fmaxf(a3, a4), p45 = fmaxf(a4, a5), p56 = fmaxf(a5, a6);
        float o0 = fmaxf(fmaxf(p01, p23), a4);    // max(a0..a4)
        float o1 = fmaxf(fmaxf(p12, p34), a5);    // max(a1..a5)
        float o2 = fmaxf(fmaxf(p23, p45), a6);    // max(a2..a6)
        float o3 = fmaxf(fmaxf(p34, p56), a7);    // max(a3..a7)
        float4 ctr = *(float4*)&sT[ty + 2][tx4 + 4];
        float o[4] = { o0, o1, o2, o3 };
        float c[4] = { ctr.x, ctr.y, ctr.z, ctr.w };
        #pragma unroll
        for (int j = 0; j < 4; ++j) {
            if (c[j] > SCORES_TH && c[j] == o[j]) {
                unsigned idx = (unsigned)((y0 + ty) * W + (x0 + tx4 + j));
                unsigned long long key =
                    ((unsigned long long)__float_as_uint(c[j]) << 32) | (unsigned)(~idx);
                unsigned p = atomicAdd(&lcnt, 1u);
                if (p < CBUF) cbuf[p] = key;
            }
        }
    }
    __syncthreads();

    // ---- P4: one global atomic per block, coalesced flush -----------------
    unsigned n = lcnt; if (n > CBUF) n = CBUF;
    if (tid == 0) lbase = atomicAdd(&counts[b * CSTRIDE], n);
    __syncthreads();
    unsigned base = lbase;
    for (unsigned k = tid; k < n; k += 256)
        if (base + k < CAP) cand[(size_t)b * CAP + base + k] = cbuf[k];
}

// ---------------------------------------------------------------------------
// K2: histogram -> suffix-sum scan -> threshold T -> bucket-grouped scatter.
// G[b][bk] = #{keys in buckets >= bk}. 1024 threads/block, one block/batch.
// ---------------------------------------------------------------------------
__global__ __launch_bounds__(1024) void select_thresh(
    const unsigned* __restrict__ counts,
    const unsigned long long* __restrict__ cand,
    unsigned long long* __restrict__ sel,
    unsigned* __restrict__ selC,
    unsigned* __restrict__ G)
{
    const int b = blockIdx.x;
    __shared__ unsigned I[NB + 1];
    __shared__ unsigned csum[1024];
    __shared__ int Tsh;
    const int tid = threadIdx.x;

    for (int i = tid; i < NB + 1; i += 1024) I[i] = 0;
    if (tid == 0) Tsh = 0;
    __syncthreads();

    unsigned M = counts[b * CSTRIDE]; if (M > CAP) M = CAP;
    const unsigned long long* cb = cand + (size_t)b * CAP;

    for (unsigned i = tid; i < M; i += 1024) {
        unsigned bits = (unsigned)(cb[i] >> 32);
        int bk = (int)(bits >> 12) - OFFB;
        bk = bk < 0 ? 0 : (bk >= NB ? NB - 1 : bk);
        atomicAdd(&I[bk], 1u);
    }
    __syncthreads();

    // suffix-sum over descending bk; r = NB-1-bk, chunk of 5 per thread
    unsigned local = 0;
    #pragma unroll
    for (int u = 0; u < 5; ++u) {
        int r = tid * 5 + u;
        if (r < NB) local += I[NB - 1 - r];
    }
    csum[tid] = local;
    __syncthreads();
    for (int off = 1; off < 1024; off <<= 1) {      // Hillis-Steele inclusive
        unsigned v = (tid >= off) ? csum[tid - off] : 0u;
        __syncthreads();
        csum[tid] += v;
        __syncthreads();
    }
    unsigned run = (tid == 0) ? 0u : csum[tid - 1];
    #pragma unroll
    for (int u = 0; u < 5; ++u) {
        int r = tid * 5 + u;
        if (r < NB) {
            int bk = NB - 1 - r;
            run += I[bk];
            I[bk] = run;          // I becomes inclusive suffix sum
        }
    }
    __syncthreads();

    // T = max bk with I[bk] >= TOPK (0 if total < TOPK -> select all)
    int localT = -1;
    #pragma unroll
    for (int u = 0; u < 5; ++u) {
        int r = tid * 5 + u;
        if (r < NB) {
            int bk = NB - 1 - r;
            if (I[bk] >= TOPK && bk > localT) localT = bk;
        }
    }
    if (localT >= 0) atomicMax(&Tsh, localT);
    __syncthreads();
    const int T = Tsh;
    if (tid == 0) selC[b] = I[T];

    // publish segment table G before gather mutates I
    unsigned* Gb = G + (size_t)b * GSTRIDE;
    for (int i = tid; i < NB + 1; i += 1024) Gb[i] = I[i];
    __syncthreads();

    // bucket-grouped scatter: cursor of bucket bk is I[bk+1] (segment start)
    for (unsigned i = tid; i < M; i += 1024) {
        unsigned long long key = cb[i];
        unsigned bits = (unsigned)(key >> 32);
        int bk = (int)(bits >> 12) - OFFB;
        bk = bk < 0 ? 0 : (bk >= NB ? NB - 1 : bk);
        if (bk >= T) {
            unsigned p = atomicAdd(&I[bk + 1], 1u);
            if (p < SELCAP) sel[(size_t)b * SELCAP + p] = key;
        }
    }
}

// ---------------------------------------------------------------------------
// K3: two-level exact rank: rank = G[bk+1] + #{same-bucket keys > mine},
// then 5x5 softmax refinement, scatter to out[rank]. No LDS.
// ---------------------------------------------------------------------------
__global__ __launch_bounds__(256) void rank_refine(
    const float* __restrict__ s,
    const unsigned long long* __restrict__ sel,
    const unsigned* __restrict__ selC,
    const unsigned* __restrict__ G,
    float* __restrict__ out)
{
    const int b = blockIdx.y;
    const unsigned C = selC[b];
    const unsigned i = blockIdx.x * 256u + threadIdx.x;
    if (i >= C) return;

    const unsigned long long* sb = sel + (size_t)b * SELCAP;
    const unsigned long long my = sb[i];
    unsigned bits = (unsigned)(my >> 32);
    int bk = (int)(bits >> 12) - OFFB;
    bk = bk < 0 ? 0 : (bk >= NB ? NB - 1 : bk);

    const unsigned* Gb = G + (size_t)b * GSTRIDE;
    const unsigned start = Gb[bk + 1], end = Gb[bk];
    unsigned rank = start;
    for (unsigned j = start; j < end; ++j)
        rank += (sb[j] > my) ? 1u : 0u;
    if (rank >= TOPK) return;

    float v = __uint_as_float(bits);
    unsigned idx = ~((unsigned)my);
    int y = (int)(idx >> 10), x = (int)(idx & 1023);

    const float* smb = s + (size_t)b * (H * W);
    float wsum = 0.f, ox = 0.f, oy = 0.f;
    #pragma unroll
    for (int dy = -2; dy <= 2; ++dy) {
        #pragma unroll
        for (int dx = -2; dx <= 2; ++dx) {
            int yy = y + dy, xx = x + dx;
            bool inb = (yy >= 0 && yy < H && xx >= 0 && xx < W);
            int yc = min(max(yy, 0), H - 1), xc = min(max(xx, 0), W - 1);
            float p = smb[yc * W + xc];
            float lg = inb ? p * 10.0f : -1e9f;   // 1/TEMPERATURE = 10
            float e = expf(lg);
            wsum += e; ox += e * (float)dx; oy += e * (float)dy;
        }
    }
    float offx = ox / wsum, offy = oy / wsum;
    out[((size_t)b * TOPK + rank) * 2 + 0] = (float)x + offx;
    out[((size_t)b * TOPK + rank) * 2 + 1] = (float)y + offy;
    out[(size_t)B * TOPK * 2 + (size_t)b * TOPK + rank] = v;
}

// ---------------------------------------------------------------------------
extern "C" void kernel_launch(void* const* d_in, const int* in_sizes, int n_in,
                              void* d_out, int out_size, void* d_ws, size_t ws_size,
                              hipStream_t stream)
{
    const float* s = (const float*)d_in[0];
    float* out = (float*)d_out;
    char* ws = (char*)d_ws;

    size_t off = 0;
    unsigned* counts        = (unsigned*)(ws + off);  off += 2048;
    unsigned* selC          = (unsigned*)(ws + off);  off += 64;
    unsigned* G             = (unsigned*)(ws + off);  off += (size_t)B * GSTRIDE * 4;
    unsigned long long* sel = (unsigned long long*)(ws + off); off += (size_t)B * SELCAP * 8;
    unsigned long long* cand= (unsigned long long*)(ws + off);

    hipMemsetAsync(counts, 0, 2048, stream);
    hipMemsetAsync(d_out, 0, (size_t)out_size * sizeof(float), stream);

    nms_compact<<<dim3(32, 32, B), dim3(256), 0, stream>>>(s, counts, cand);
    select_thresh<<<dim3(B), dim3(1024), 0, stream>>>(counts, cand, sel, selC, G);
    rank_refine<<<dim3(SELCAP / 256, B), dim3(256), 0, stream>>>(s, sel, selC, G, out);
}